// Round 6
// baseline (14.882 us; speedup 1.0000x reference)
//
#include <hip/hip_runtime.h>

#define BB 64
#define KK 128
#define DD 128

typedef __attribute__((ext_vector_type(8))) short bf16x8;
typedef __attribute__((ext_vector_type(4))) float f32x4;
typedef _Float16 half2v __attribute__((ext_vector_type(2)));
typedef __fp16 fp16x2 __attribute__((ext_vector_type(2)));

__device__ __forceinline__ unsigned cvt_pk_bf16(float x, float y) {
    unsigned r;
    asm("v_cvt_pk_bf16_f32 %0, %1, %2" : "=v"(r) : "v"(x), "v"(y));
    return r;
}

__device__ __forceinline__ unsigned cvt_pkrtz_u(float x, float y) {
    const fp16x2 pk = __builtin_amdgcn_cvt_pkrtz(x, y);
    return __builtin_bit_cast(unsigned, pk);
}

// relu(a+b) on packed f16 pairs
__device__ __forceinline__ unsigned pk_add_relu(unsigned a, unsigned b) {
    unsigned s, r;
    asm("v_pk_add_f16 %0, %1, %2" : "=v"(s) : "v"(a), "v"(b));
    asm("v_pk_max_f16 %0, %1, 0" : "=v"(r) : "v"(s));
    return r;
}

__device__ __forceinline__ float dot2acc(unsigned a, unsigned b, float c) {
#if __has_builtin(__builtin_amdgcn_fdot2)
    return __builtin_amdgcn_fdot2(__builtin_bit_cast(half2v, a),
                                  __builtin_bit_cast(half2v, b), c, false);
#else
    float r;
    asm("v_dot2_f32_f16 %0, %1, %2, %3" : "=v"(r) : "v"(a), "v"(b), "v"(c));
    return r;
#endif
}

// Grid = 512 (b x it(2) x jt(4)): out tile 64 i x 32 j. Block = 256 threads
// (4 waves) -> 2 blocks/CU, independent phases overlap across blocks.
// LDS (38528 B, no union):
//   SA  bf16[96][128] @ word 0     rows 0-63: slots i-tile, 64-95: slots j-tile
//       XOR-swizzled per 16B block: blk' = blk ^ (row & 7)
//   LsP half2[64][36] @ word 6144, RsP half2[32][36] @ word 8448,
//   W2p half2[32]     @ word 9600
//   half2 word col c holds h-pair (32*(c>>4)+(c&15), +16)
// W1 never staged: each wave loads its B-fragments global->reg.
// Wave roles: side = w>>1 (0: L-GEMM 64 rows, 1: R-GEMM 32 rows), grp = w&1
// (h-half: h in [32*grp, 32*grp+32)).
__global__ __launch_bounds__(256, 2) void fused_kernel(
    const float* __restrict__ slots, const float* __restrict__ W1,
    const float* __restrict__ b1, const float* __restrict__ W2,
    const float* __restrict__ b2p, float* __restrict__ out)
{
    __shared__ unsigned smem_w[9632];
    char* smem = (char*)smem_w;

    const int t   = threadIdx.x;
    const int blk = blockIdx.x;
    const int b   = blk >> 3;
    const int it  = (blk >> 2) & 1;
    const int jt  = blk & 3;

    const int lane = t & 63;
    const int w    = t >> 6;                 // 0..3
    const int lr   = lane & 15;
    const int lk   = lane >> 4;
    const int side = w >> 1;                 // 0: L, 1: R
    const int grp  = w & 1;                  // h-half

    const float b2 = *b2p;
    const float b1lo = (side == 0) ? b1[grp * 32 + lr]      : 0.0f;
    const float b1hi = (side == 0) ? b1[grp * 32 + 16 + lr] : 0.0f;
    float w2lo = 0.f, w2hi = 0.f;
    if (t < 32) {
        const int hl = (t & 15) + 32 * (t >> 4);
        w2lo = W2[hl]; w2hi = W2[hl + 16];
    }

    // ---------------- B-fragments: W1 global -> reg (bf16 packed) ----------------
    bf16x8 bfr[2][4];
#pragma unroll
    for (int n = 0; n < 2; ++n)
#pragma unroll
        for (int kf = 0; kf < 4; ++kf) {
            const int rowB = grp * 32 + n * 16 + lr;
            const float* p = W1 + rowB * 256 + side * 128 + kf * 32 + lk * 8;
            const float4 f0 = *reinterpret_cast<const float4*>(p);
            const float4 f1 = *reinterpret_cast<const float4*>(p + 4);
            uint4 pk;
            pk.x = cvt_pk_bf16(f0.x, f0.y); pk.y = cvt_pk_bf16(f0.z, f0.w);
            pk.z = cvt_pk_bf16(f1.x, f1.y); pk.w = cvt_pk_bf16(f1.z, f1.w);
            bfr[n][kf] = __builtin_bit_cast(bf16x8, pk);
        }

    // ---------------- stage slots tiles as swizzled bf16 ----------------
    {
        const float* srcI = slots + ((size_t)(b * KK) + it * 64) * DD;
        const float* srcJ = slots + ((size_t)(b * KK) + jt * 32) * DD;
#pragma unroll
        for (int x0 = 0; x0 < 1536; x0 += 256) {          // 96 rows x 16 16B-blocks
            const int x = x0 + t;
            const int row = x >> 4, cb = x & 15;
            const float* src = (row < 64 ? srcI + row * DD
                                         : srcJ + (row - 64) * DD) + cb * 8;
            const float4 f0 = *reinterpret_cast<const float4*>(src);
            const float4 f1 = *reinterpret_cast<const float4*>(src + 4);
            uint4 pk;
            pk.x = cvt_pk_bf16(f0.x, f0.y); pk.y = cvt_pk_bf16(f0.z, f0.w);
            pk.z = cvt_pk_bf16(f1.x, f1.y); pk.w = cvt_pk_bf16(f1.z, f1.w);
            *reinterpret_cast<uint4*>(smem + row * 256 + ((cb ^ (row & 7)) << 4)) = pk;
        }
    }
    __syncthreads();

    // ---------------- MFMA + spill (one phase: disjoint LDS regions) ----------------
    f32x4 acc[4][2];
#pragma unroll
    for (int m = 0; m < 4; ++m)
#pragma unroll
        for (int n = 0; n < 2; ++n) acc[m][n] = f32x4{0.f, 0.f, 0.f, 0.f};

#pragma unroll
    for (int m = 0; m < 4; ++m) {
        if (side == 1 && m >= 2) continue;               // R tile has 32 rows
#pragma unroll
        for (int kf = 0; kf < 4; ++kf) {
            const int row = side * 64 + 16 * m + lr;
            const int cb  = kf * 4 + lk;
            const bf16x8 af = *reinterpret_cast<const bf16x8*>(
                smem + row * 256 + ((cb ^ (row & 7)) << 4));
#pragma unroll
            for (int n = 0; n < 2; ++n)
                acc[m][n] = __builtin_amdgcn_mfma_f32_16x16x32_bf16(
                    af, bfr[n][kf], acc[m][n], 0, 0, 0);
        }
    }

    {
        unsigned* dst = smem_w + (side ? 8448 : 6144);
#pragma unroll
        for (int m = 0; m < 4; ++m) {
            if (side == 1 && m >= 2) continue;
#pragma unroll
            for (int r = 0; r < 4; ++r) {
                const int row = 16 * m + 4 * lk + r;     // D: row = 4*(lane>>4)+reg
                dst[row * 36 + grp * 16 + lr] =
                    cvt_pkrtz_u(acc[m][0][r] + b1lo, acc[m][1][r] + b1hi);
            }
        }
        if (t < 32) smem_w[9600 + t] = cvt_pkrtz_u(w2lo, w2hi);
    }
    __syncthreads();

    // ---------------- pairwise: sigmoid(b2 + sum relu(L+R)*W2) ----------------
    const int tx = t & 15;                  // j = tx + 16*jj (jj<2)
    const int ty = t >> 4;                  // i = ty + 16*ii (ii<4)
    const unsigned* LsP = smem_w + 6144;
    const unsigned* RsP = smem_w + 8448;
    const unsigned* W2p = smem_w + 9600;

    uint4 w2r[8];
#pragma unroll
    for (int s = 0; s < 8; ++s)
        w2r[s] = *reinterpret_cast<const uint4*>(W2p + s * 4);

    float pacc[4][2] = {};
    uint4 l4a[4], r4a[2], l4b[4], r4b[2];

#define LD_STEP(L4, R4, s)                                                        \
    {                                                                             \
        _Pragma("unroll") for (int ii = 0; ii < 4; ++ii)                          \
            L4[ii] = *reinterpret_cast<const uint4*>(LsP + (ty + 16 * ii) * 36 + (s) * 4); \
        _Pragma("unroll") for (int jj = 0; jj < 2; ++jj)                          \
            R4[jj] = *reinterpret_cast<const uint4*>(RsP + (tx + 16 * jj) * 36 + (s) * 4); \
    }

#define COMPUTE_STEP(L4, R4, s)                                                   \
    {                                                                             \
        _Pragma("unroll") for (int ii = 0; ii < 4; ++ii)                          \
        _Pragma("unroll") for (int jj = 0; jj < 2; ++jj) {                        \
            float a = pacc[ii][jj];                                               \
            a = dot2acc(pk_add_relu(L4[ii].x, R4[jj].x), w2r[s].x, a);            \
            a = dot2acc(pk_add_relu(L4[ii].y, R4[jj].y), w2r[s].y, a);            \
            a = dot2acc(pk_add_relu(L4[ii].z, R4[jj].z), w2r[s].z, a);            \
            a = dot2acc(pk_add_relu(L4[ii].w, R4[jj].w), w2r[s].w, a);            \
            pacc[ii][jj] = a;                                                     \
        }                                                                         \
    }

    LD_STEP(l4a, r4a, 0)
#pragma unroll
    for (int sp = 0; sp < 4; ++sp) {
        LD_STEP(l4b, r4b, 2 * sp + 1)
        COMPUTE_STEP(l4a, r4a, 2 * sp)
        if (sp < 3) LD_STEP(l4a, r4a, 2 * sp + 2)
        COMPUTE_STEP(l4b, r4b, 2 * sp + 1)
    }
#undef LD_STEP
#undef COMPUTE_STEP

#pragma unroll
    for (int ii = 0; ii < 4; ++ii) {
        const int gi = it * 64 + ty + 16 * ii;
        float* orow = out + ((size_t)(b * KK) + gi) * KK + jt * 32;
#pragma unroll
        for (int jj = 0; jj < 2; ++jj) {
            const int jl = tx + 16 * jj;
            const int gj = jt * 32 + jl;
            const float xv = pacc[ii][jj] + b2;
            const float sg = 1.0f / (1.0f + __expf(-xv));
            orow[jl] = (gi == gj) ? 0.0f : sg;
        }
    }
}

extern "C" void kernel_launch(void* const* d_in, const int* in_sizes, int n_in,
                              void* d_out, int out_size, void* d_ws, size_t ws_size,
                              hipStream_t stream) {
    const float* slots = (const float*)d_in[0];
    const float* W1    = (const float*)d_in[1];
    const float* b1    = (const float*)d_in[2];
    const float* W2    = (const float*)d_in[3];
    const float* b2    = (const float*)d_in[4];
    float* out = (float*)d_out;
    (void)d_ws; (void)ws_size; (void)in_sizes; (void)n_in; (void)out_size;

    fused_kernel<<<BB * 8, 256, 0, stream>>>(slots, W1, b1, W2, b2, out);
}